// Round 1
// baseline (439.606 us; speedup 1.0000x reference)
//
#include <hip/hip_runtime.h>
#include <hip/hip_bf16.h>

typedef __attribute__((ext_vector_type(8))) short bf16x8;
typedef __attribute__((ext_vector_type(4))) float f32x4;

#define NB 16384
#define NE 31

static __device__ __forceinline__ unsigned short f2b(float f) {
  unsigned int u = __builtin_bit_cast(unsigned int, f);
  return (unsigned short)((u + 0x7fffu + ((u >> 16) & 1u)) >> 16);
}
static __device__ __forceinline__ float b2f(unsigned short h) {
  return __builtin_bit_cast(float, ((unsigned int)h) << 16);
}

// ---------------- K0: convert 6 weight matrices (256x256 f32) to bf16 ----------------
// ws layout order: Wq, Wk, Wv, Wok, Wov, Wc (each 65536 elems)
__global__ void k0_conv(const float* __restrict__ wq, const float* __restrict__ wk,
                        const float* __restrict__ wv, const float* __restrict__ wok,
                        const float* __restrict__ wov, const float* __restrict__ wc,
                        unsigned short* __restrict__ out) {
  int idx = blockIdx.x * 256 + threadIdx.x;  // 0..65535
  int m = blockIdx.y;
  const float* s;
  if (m == 0) s = wq;
  else if (m == 1) s = wk;
  else if (m == 2) s = wv;
  else if (m == 3) s = wok;
  else if (m == 4) s = wov;
  else s = wc;
  out[m * 65536 + idx] = f2b(s[idx]);
}

// ---------------- K1: qkv[b][n] = sum_k ego[b][k] * Wqkv[n][k]; q part scaled 1/8 ----
// Wqkv = bf16 [768][256] (q,k,v rows concatenated). Output bf16 qkv[b][768].
__global__ __launch_bounds__(256, 2)
void k1_qkv(const float* __restrict__ ego, const unsigned short* __restrict__ wqkv,
            unsigned short* __restrict__ qkv) {
  __shared__ __align__(16) unsigned short Al[128 * 256];  // 64KB, swizzled
  const int tid = threadIdx.x;
  const int bM = blockIdx.x * 128, bN = blockIdx.y * 64;
#pragma unroll
  for (int it = 0; it < 16; ++it) {
    int c = tid + it * 256;                 // 4096 chunks of 8 f32
    int row = c >> 5, k8 = c & 31;
    const float4* g = (const float4*)(ego + (size_t)(bM + row) * 256 + k8 * 8);
    float4 x = g[0], y = g[1];
    float t[8] = {x.x, x.y, x.z, x.w, y.x, y.y, y.z, y.w};
    bf16x8 v;
#pragma unroll
    for (int j = 0; j < 8; ++j) v[j] = (short)f2b(t[j]);
    int byteoff = row * 512 + ((k8 * 16) ^ ((row & 7) << 4));
    *(bf16x8*)((char*)Al + byteoff) = v;
  }
  __syncthreads();
  const int w = tid >> 6, lane = tid & 63, lr = lane & 15, lkg = lane >> 4;
  f32x4 acc[2][4];
#pragma unroll
  for (int mt = 0; mt < 2; ++mt)
#pragma unroll
    for (int nt = 0; nt < 4; ++nt) acc[mt][nt] = (f32x4){0.f, 0.f, 0.f, 0.f};
#pragma unroll
  for (int kk = 0; kk < 8; ++kk) {
    int kidx = kk * 32 + lkg * 8;
    bf16x8 bfr[4], afr[2];
#pragma unroll
    for (int nt = 0; nt < 4; ++nt)
      bfr[nt] = *(const bf16x8*)(wqkv + (size_t)(bN + nt * 16 + lr) * 256 + kidx);
#pragma unroll
    for (int mt = 0; mt < 2; ++mt) {
      int row = w * 32 + mt * 16 + lr;
      int byteoff = row * 512 + ((kidx * 2) ^ ((row & 7) << 4));
      afr[mt] = *(const bf16x8*)((const char*)Al + byteoff);
    }
#pragma unroll
    for (int mt = 0; mt < 2; ++mt)
#pragma unroll
      for (int nt = 0; nt < 4; ++nt)
        acc[mt][nt] = __builtin_amdgcn_mfma_f32_16x16x32_bf16(afr[mt], bfr[nt], acc[mt][nt], 0, 0, 0);
  }
#pragma unroll
  for (int mt = 0; mt < 2; ++mt)
#pragma unroll
    for (int nt = 0; nt < 4; ++nt)
#pragma unroll
      for (int j = 0; j < 4; ++j) {
        int row = bM + w * 32 + mt * 16 + lkg * 4 + j;
        int col = bN + nt * 16 + lr;
        float v = acc[mt][nt][j];
        if (col < 256) v *= 0.125f;  // fold 1/sqrt(D_HEAD) into q
        qkv[(size_t)row * 768 + col] = f2b(v);
      }
}

// ---------------- K2: fused others-projection + attention -----------------------------
// One workgroup = 4 batch items, 4 waves = 4 heads.
__global__ __launch_bounds__(256, 1)
void k2_attn(const float* __restrict__ others, const int* __restrict__ mask,
             const unsigned short* __restrict__ wkv,   // Wok (65536) then Wov (65536) bf16
             const unsigned short* __restrict__ qkv,   // [NB][768] bf16
             unsigned short* __restrict__ valout,      // [NB][256] bf16
             float* __restrict__ attnout) {            // [NB][128] f32
  __shared__ __align__(16) unsigned short Al[128 * 256];     // 64KB others tile (swizzled)
  __shared__ __align__(16) unsigned short Csub[4][124 * 72]; // per-wave K/V tile, stride 72
  __shared__ __align__(16) unsigned short qk_l[4 * 768];     // 4 items x (q,k,v)
  __shared__ float sco_l[4][4][32];                          // [wave][item][key]
  __shared__ float p_l[4][4][32];
  const int tid = threadIdx.x;
  const size_t b0 = (size_t)blockIdx.x * 4;
  // stage others (4 items x 31 rows x 256) -> bf16 swizzled LDS; rows 124..127 zero
  const float4* gb = (const float4*)(others + b0 * (NE * 256));
#pragma unroll
  for (int it = 0; it < 16; ++it) {
    int c = tid + it * 256;
    int row = c >> 5, k8 = c & 31;
    bf16x8 v;
    if (c < 3968) {
      float4 x = gb[c * 2], y = gb[c * 2 + 1];
      float t[8] = {x.x, x.y, x.z, x.w, y.x, y.y, y.z, y.w};
#pragma unroll
      for (int j = 0; j < 8; ++j) v[j] = (short)f2b(t[j]);
    } else {
      v = (bf16x8){0, 0, 0, 0, 0, 0, 0, 0};
    }
    int byteoff = row * 512 + ((k8 * 16) ^ ((row & 7) << 4));
    *(bf16x8*)((char*)Al + byteoff) = v;
  }
  // stage ego q,k,v for the 4 items (384 chunks of 8 bf16)
  for (int c = tid; c < 384; c += 256)
    *(bf16x8*)(qk_l + c * 8) = *(const bf16x8*)(qkv + b0 * 768 + c * 8);
  __syncthreads();

  const int w = tid >> 6, lane = tid & 63, lr = lane & 15, lkg = lane >> 4;
  unsigned short* C = Csub[w];

#pragma unroll 1
  for (int part = 0; part < 2; ++part) {  // 0: K (Wok), 1: V (Wov)
    const unsigned short* W = wkv + part * 65536;
    f32x4 acc[8][4];
#pragma unroll
    for (int mt = 0; mt < 8; ++mt)
#pragma unroll
      for (int nt = 0; nt < 4; ++nt) acc[mt][nt] = (f32x4){0.f, 0.f, 0.f, 0.f};
    for (int kk = 0; kk < 8; ++kk) {
      int kidx = kk * 32 + lkg * 8;
      bf16x8 bfr[4];
#pragma unroll
      for (int nt = 0; nt < 4; ++nt)
        bfr[nt] = *(const bf16x8*)(W + (size_t)(w * 64 + nt * 16 + lr) * 256 + kidx);
#pragma unroll
      for (int mt = 0; mt < 8; ++mt) {
        int row = mt * 16 + lr;
        int byteoff = row * 512 + ((kidx * 2) ^ ((row & 7) << 4));
        bf16x8 a = *(const bf16x8*)((const char*)Al + byteoff);
#pragma unroll
        for (int nt = 0; nt < 4; ++nt)
          acc[mt][nt] = __builtin_amdgcn_mfma_f32_16x16x32_bf16(a, bfr[nt], acc[mt][nt], 0, 0, 0);
      }
    }
    // write K_h / V_h tile to per-wave LDS (rows >= 124 are padding -> dropped)
#pragma unroll
    for (int mt = 0; mt < 8; ++mt)
#pragma unroll
      for (int nt = 0; nt < 4; ++nt)
#pragma unroll
        for (int j = 0; j < 4; ++j) {
          int row = mt * 16 + lkg * 4 + j;
          if (row < 124) C[row * 72 + nt * 16 + lr] = f2b(acc[mt][nt][j]);
        }

    if (part == 0) {
      // scores for keys 1..31 (others): lane -> rows {lane, lane+64}
#pragma unroll
      for (int rep = 0; rep < 2; ++rep) {
        int r = lane + rep * 64;
        if (r < 124) {
          int item = r / 31, e = r - item * 31;
          const unsigned short* q = qk_l + item * 768 + w * 64;
          const unsigned short* Kr = C + r * 72;
          float s = 0.f;
#pragma unroll
          for (int c8 = 0; c8 < 8; ++c8) {
            bf16x8 qv = *(const bf16x8*)(q + c8 * 8);
            bf16x8 kv = *(const bf16x8*)(Kr + c8 * 8);
#pragma unroll
            for (int j = 0; j < 8; ++j)
              s += b2f((unsigned short)qv[j]) * b2f((unsigned short)kv[j]);
          }
          sco_l[w][item][1 + e] = s;
        }
      }
      // ego key score (key 0): 16 lanes per item, partial dot + shfl reduce
      {
        int item = lkg;
        const unsigned short* q = qk_l + item * 768 + w * 64;
        const unsigned short* ke = qk_l + item * 768 + 256 + w * 64;
        float s = 0.f;
#pragma unroll
        for (int j = 0; j < 4; ++j)
          s += b2f(q[lr + j * 16]) * b2f(ke[lr + j * 16]);
#pragma unroll
        for (int off = 1; off < 16; off <<= 1) s += __shfl_xor(s, off, 16);
        if (lr == 0) sco_l[w][item][0] = s;
      }
      // masked softmax over 32 keys; two (item,key) per lane
#pragma unroll
      for (int rep = 0; rep < 2; ++rep) {
        int item = (lane >> 5) + rep * 2;
        int key = lane & 31;
        float s = sco_l[w][item][key];
        if (mask[(b0 + item) * 32 + key] != 0) s = -1e9f;
        float mx = s;
#pragma unroll
        for (int off = 1; off < 32; off <<= 1) mx = fmaxf(mx, __shfl_xor(mx, off, 32));
        float ex = __expf(s - mx);
        float sm = ex;
#pragma unroll
        for (int off = 1; off < 32; off <<= 1) sm += __shfl_xor(sm, off, 32);
        float p = ex / sm;
        p_l[w][item][key] = p;
        attnout[(b0 + item) * 128 + w * 32 + key] = p;
      }
    } else {
      // PV: value[b][h*64+d] = p0*v_ego[d] + sum_e p[e+1]*V[e][d]
#pragma unroll
      for (int rep = 0; rep < 2; ++rep) {
        int item = (lane >> 5) + rep * 2;
#pragma unroll
        for (int dd = 0; dd < 2; ++dd) {
          int d = (lane & 31) + dd * 32;
          float a = p_l[w][item][0] * b2f(qk_l[item * 768 + 512 + w * 64 + d]);
          const unsigned short* Vr = C + (item * 31) * 72 + d;
#pragma unroll
          for (int e = 0; e < 31; ++e)
            a = fmaf(p_l[w][item][1 + e], b2f(Vr[e * 72]), a);
          valout[(b0 + item) * 256 + w * 64 + d] = f2b(a);
        }
      }
    }
  }
}

// ---------------- K3: res = (value @ Wc^T + ego) * 0.5 --------------------------------
__global__ __launch_bounds__(256, 2)
void k3_out(const unsigned short* __restrict__ val, const unsigned short* __restrict__ wc,
            const float* __restrict__ ego, float* __restrict__ out) {
  __shared__ __align__(16) unsigned short Al[128 * 256];
  const int tid = threadIdx.x;
  const int bM = blockIdx.x * 128, bN = blockIdx.y * 64;
#pragma unroll
  for (int it = 0; it < 16; ++it) {
    int c = tid + it * 256;
    int row = c >> 5, k8 = c & 31;
    bf16x8 v = *(const bf16x8*)(val + (size_t)(bM + row) * 256 + k8 * 8);
    int byteoff = row * 512 + ((k8 * 16) ^ ((row & 7) << 4));
    *(bf16x8*)((char*)Al + byteoff) = v;
  }
  __syncthreads();
  const int w = tid >> 6, lane = tid & 63, lr = lane & 15, lkg = lane >> 4;
  f32x4 acc[2][4];
#pragma unroll
  for (int mt = 0; mt < 2; ++mt)
#pragma unroll
    for (int nt = 0; nt < 4; ++nt) acc[mt][nt] = (f32x4){0.f, 0.f, 0.f, 0.f};
#pragma unroll
  for (int kk = 0; kk < 8; ++kk) {
    int kidx = kk * 32 + lkg * 8;
    bf16x8 bfr[4], afr[2];
#pragma unroll
    for (int nt = 0; nt < 4; ++nt)
      bfr[nt] = *(const bf16x8*)(wc + (size_t)(bN + nt * 16 + lr) * 256 + kidx);
#pragma unroll
    for (int mt = 0; mt < 2; ++mt) {
      int row = w * 32 + mt * 16 + lr;
      int byteoff = row * 512 + ((kidx * 2) ^ ((row & 7) << 4));
      afr[mt] = *(const bf16x8*)((const char*)Al + byteoff);
    }
#pragma unroll
    for (int mt = 0; mt < 2; ++mt)
#pragma unroll
      for (int nt = 0; nt < 4; ++nt)
        acc[mt][nt] = __builtin_amdgcn_mfma_f32_16x16x32_bf16(afr[mt], bfr[nt], acc[mt][nt], 0, 0, 0);
  }
#pragma unroll
  for (int mt = 0; mt < 2; ++mt)
#pragma unroll
    for (int nt = 0; nt < 4; ++nt)
#pragma unroll
      for (int j = 0; j < 4; ++j) {
        int row = bM + w * 32 + mt * 16 + lkg * 4 + j;
        int col = bN + nt * 16 + lr;
        out[(size_t)row * 256 + col] = (acc[mt][nt][j] + ego[(size_t)row * 256 + col]) * 0.5f;
      }
}

extern "C" void kernel_launch(void* const* d_in, const int* in_sizes, int n_in,
                              void* d_out, int out_size, void* d_ws, size_t ws_size,
                              hipStream_t stream) {
  const float* ego    = (const float*)d_in[0];
  const float* others = (const float*)d_in[1];
  const int*   mask   = (const int*)d_in[2];
  const float* wq  = (const float*)d_in[3];
  const float* wk  = (const float*)d_in[4];
  const float* wv  = (const float*)d_in[5];
  const float* wok = (const float*)d_in[6];
  const float* wov = (const float*)d_in[7];
  const float* wc  = (const float*)d_in[8];

  unsigned short* ws_w   = (unsigned short*)d_ws;            // 6*65536 bf16
  unsigned short* ws_qkv = ws_w + 6 * 65536;                 // NB*768 bf16
  unsigned short* ws_val = ws_qkv + (size_t)NB * 768;        // NB*256 bf16

  float* res  = (float*)d_out;                               // NB*256 f32
  float* attn = res + (size_t)NB * 256;                      // NB*128 f32

  hipLaunchKernelGGL(k0_conv, dim3(256, 6), dim3(256), 0, stream,
                     wq, wk, wv, wok, wov, wc, ws_w);
  hipLaunchKernelGGL(k1_qkv, dim3(128, 12), dim3(256), 0, stream,
                     ego, ws_w, ws_qkv);
  hipLaunchKernelGGL(k2_attn, dim3(4096), dim3(256), 0, stream,
                     others, mask, ws_w + 3 * 65536, ws_qkv, ws_val, attn);
  hipLaunchKernelGGL(k3_out, dim3(128, 4), dim3(256), 0, stream,
                     ws_val, ws_w + 5 * 65536, ego, res);
}

// Round 2
// 367.337 us; speedup vs baseline: 1.1967x; 1.1967x over previous
//
#include <hip/hip_runtime.h>
#include <hip/hip_bf16.h>

typedef __attribute__((ext_vector_type(8))) short bf16x8;
typedef __attribute__((ext_vector_type(4))) float f32x4;

#define NB 16384
#define NE 31

static __device__ __forceinline__ unsigned short f2b(float f) {
  unsigned int u = __builtin_bit_cast(unsigned int, f);
  return (unsigned short)((u + 0x7fffu + ((u >> 16) & 1u)) >> 16);
}
static __device__ __forceinline__ float b2f(unsigned short h) {
  return __builtin_bit_cast(float, ((unsigned int)h) << 16);
}

// ---------------- K0: convert 6 weight matrices (256x256 f32) to bf16 ----------------
// ws layout order: Wq, Wk, Wv, Wok, Wov, Wc (each 65536 elems)
__global__ void k0_conv(const float* __restrict__ wq, const float* __restrict__ wk,
                        const float* __restrict__ wv, const float* __restrict__ wok,
                        const float* __restrict__ wov, const float* __restrict__ wc,
                        unsigned short* __restrict__ out) {
  int idx = blockIdx.x * 256 + threadIdx.x;  // 0..65535
  int m = blockIdx.y;
  const float* s;
  if (m == 0) s = wq;
  else if (m == 1) s = wk;
  else if (m == 2) s = wv;
  else if (m == 3) s = wok;
  else if (m == 4) s = wov;
  else s = wc;
  out[m * 65536 + idx] = f2b(s[idx]);
}

// ---------------- K1: qkv[b][n] = sum_k ego[b][k] * Wqkv[n][k]; q part scaled 1/8 ----
// Wqkv = bf16 [768][256] (q,k,v rows concatenated). Output bf16 qkv[b][768].
__global__ __launch_bounds__(256, 2)
void k1_qkv(const float* __restrict__ ego, const unsigned short* __restrict__ wqkv,
            unsigned short* __restrict__ qkv) {
  __shared__ __align__(16) unsigned short Al[128 * 256];  // 64KB, swizzled
  const int tid = threadIdx.x;
  const int bM = blockIdx.x * 128, bN = blockIdx.y * 64;
#pragma unroll
  for (int it = 0; it < 16; ++it) {
    int c = tid + it * 256;                 // 4096 chunks of 8 f32
    int row = c >> 5, k8 = c & 31;
    const float4* g = (const float4*)(ego + (size_t)(bM + row) * 256 + k8 * 8);
    float4 x = g[0], y = g[1];
    float t[8] = {x.x, x.y, x.z, x.w, y.x, y.y, y.z, y.w};
    bf16x8 v;
#pragma unroll
    for (int j = 0; j < 8; ++j) v[j] = (short)f2b(t[j]);
    int byteoff = row * 512 + ((k8 * 16) ^ ((row & 7) << 4));
    *(bf16x8*)((char*)Al + byteoff) = v;
  }
  __syncthreads();
  const int w = tid >> 6, lane = tid & 63, lr = lane & 15, lkg = lane >> 4;
  f32x4 acc[2][4];
#pragma unroll
  for (int mt = 0; mt < 2; ++mt)
#pragma unroll
    for (int nt = 0; nt < 4; ++nt) acc[mt][nt] = (f32x4){0.f, 0.f, 0.f, 0.f};
#pragma unroll
  for (int kk = 0; kk < 8; ++kk) {
    int kidx = kk * 32 + lkg * 8;
    bf16x8 bfr[4], afr[2];
#pragma unroll
    for (int nt = 0; nt < 4; ++nt)
      bfr[nt] = *(const bf16x8*)(wqkv + (size_t)(bN + nt * 16 + lr) * 256 + kidx);
#pragma unroll
    for (int mt = 0; mt < 2; ++mt) {
      int row = w * 32 + mt * 16 + lr;
      int byteoff = row * 512 + ((kidx * 2) ^ ((row & 7) << 4));
      afr[mt] = *(const bf16x8*)((const char*)Al + byteoff);
    }
#pragma unroll
    for (int mt = 0; mt < 2; ++mt)
#pragma unroll
      for (int nt = 0; nt < 4; ++nt)
        acc[mt][nt] = __builtin_amdgcn_mfma_f32_16x16x32_bf16(afr[mt], bfr[nt], acc[mt][nt], 0, 0, 0);
  }
#pragma unroll
  for (int mt = 0; mt < 2; ++mt)
#pragma unroll
    for (int nt = 0; nt < 4; ++nt)
#pragma unroll
      for (int j = 0; j < 4; ++j) {
        int row = bM + w * 32 + mt * 16 + lkg * 4 + j;
        int col = bN + nt * 16 + lr;
        float v = acc[mt][nt][j];
        if (col < 256) v *= 0.125f;  // fold 1/sqrt(D_HEAD) into q
        qkv[(size_t)row * 768 + col] = f2b(v);
      }
}

// ---------------- K2: fused others-projection + attention -----------------------------
// One workgroup = 2 batch items. 8 waves: wave = head*2 + part (part 0 = K, 1 = V).
// Scores computed directly from K-wave MFMA fragments (no LDS bounce);
// PV computed directly from V-wave MFMA fragments.
__global__ __launch_bounds__(512, 4)
void k2_attn(const float* __restrict__ others, const int* __restrict__ mask,
             const unsigned short* __restrict__ wkv,   // Wok (65536) then Wov (65536) bf16
             const unsigned short* __restrict__ qkv,   // [NB][768] bf16
             unsigned short* __restrict__ valout,      // [NB][256] bf16
             float* __restrict__ attnout) {            // [NB][128] f32
  __shared__ __align__(16) unsigned short Al[64 * 256];   // 32KB others tile (swizzled bf16)
  __shared__ __align__(16) unsigned short qk_l[2 * 768];  // 2 items x (q,k,v)
  __shared__ float sco_l[4][2][32];                       // [head][item][key]
  __shared__ float p_l[4][2][32];
  const int tid = threadIdx.x;
  const size_t b0 = (size_t)blockIdx.x * 2;

  // stage others (2 items x 31 rows x 256 f32) -> bf16 swizzled LDS; rows 62,63 zero
  const float4* gb = (const float4*)(others + b0 * (NE * 256));
#pragma unroll
  for (int it = 0; it < 4; ++it) {
    int c = tid + it * 512;                 // 2048 chunks of 8 floats
    int row = c >> 5, k8 = c & 31;
    bf16x8 v;
    if (c < 1984) {
      float4 x = gb[c * 2], y = gb[c * 2 + 1];
      float t[8] = {x.x, x.y, x.z, x.w, y.x, y.y, y.z, y.w};
#pragma unroll
      for (int j = 0; j < 8; ++j) v[j] = (short)f2b(t[j]);
    } else {
      v = (bf16x8){0, 0, 0, 0, 0, 0, 0, 0};
    }
    int byteoff = row * 512 + ((k8 * 16) ^ ((row & 7) << 4));
    *(bf16x8*)((char*)Al + byteoff) = v;
  }
  // stage ego q,k,v for the 2 items (192 chunks of 8 bf16)
  if (tid < 192)
    *(bf16x8*)(qk_l + tid * 8) = *(const bf16x8*)(qkv + b0 * 768 + tid * 8);
  __syncthreads();

  const int w = tid >> 6, lane = tid & 63, lr = lane & 15, lkg = lane >> 4;
  const int head = w >> 1, part = w & 1;
  const unsigned short* W = wkv + part * 65536 + (size_t)head * 64 * 256;

  f32x4 acc[4][4];
#pragma unroll
  for (int mt = 0; mt < 4; ++mt)
#pragma unroll
    for (int nt = 0; nt < 4; ++nt) acc[mt][nt] = (f32x4){0.f, 0.f, 0.f, 0.f};

#pragma unroll
  for (int kk = 0; kk < 8; ++kk) {
    int kidx = kk * 32 + lkg * 8;
    bf16x8 bfr[4];
#pragma unroll
    for (int nt = 0; nt < 4; ++nt)
      bfr[nt] = *(const bf16x8*)(W + (size_t)(nt * 16 + lr) * 256 + kidx);
#pragma unroll
    for (int mt = 0; mt < 4; ++mt) {
      int row = mt * 16 + lr;
      int byteoff = row * 512 + ((kidx * 2) ^ ((row & 7) << 4));
      bf16x8 a = *(const bf16x8*)((const char*)Al + byteoff);
#pragma unroll
      for (int nt = 0; nt < 4; ++nt)
        acc[mt][nt] = __builtin_amdgcn_mfma_f32_16x16x32_bf16(a, bfr[nt], acc[mt][nt], 0, 0, 0);
    }
  }

  if (part == 0) {
    // ---- scores from K fragments. Lane holds K[r=mt*16+lkg*4+j][d=nt*16+lr]. ----
    float qv[2][4];
#pragma unroll
    for (int item = 0; item < 2; ++item)
#pragma unroll
      for (int nt = 0; nt < 4; ++nt)
        qv[item][nt] = b2f(qk_l[item * 768 + head * 64 + nt * 16 + lr]);
#pragma unroll
    for (int mt = 0; mt < 4; ++mt)
#pragma unroll
      for (int j = 0; j < 4; ++j) {
        int r = mt * 16 + lkg * 4 + j;
        int item = (r >= NE) ? 1 : 0;
        float s = acc[mt][0][j] * qv[item][0] + acc[mt][1][j] * qv[item][1] +
                  acc[mt][2][j] * qv[item][2] + acc[mt][3][j] * qv[item][3];
#pragma unroll
        for (int off = 1; off < 16; off <<= 1) s += __shfl_xor(s, off, 16);
        if (lr == 0 && r < 2 * NE) sco_l[head][item][1 + (r - item * NE)] = s;
      }
    // ---- ego key score ----
    if (lkg < 2) {
      int item = lkg;
      const unsigned short* q = qk_l + item * 768 + head * 64;
      const unsigned short* ke = qk_l + item * 768 + 256 + head * 64;
      float s = 0.f;
#pragma unroll
      for (int j = 0; j < 4; ++j)
        s += b2f(q[lr + j * 16]) * b2f(ke[lr + j * 16]);
#pragma unroll
      for (int off = 1; off < 16; off <<= 1) s += __shfl_xor(s, off, 16);
      if (lr == 0) sco_l[head][item][0] = s;
    }
    // ---- masked softmax: lane = item*32 + key ----
    {
      int item = lane >> 5, key = lane & 31;
      float s = sco_l[head][item][key];
      if (mask[(b0 + item) * 32 + key] != 0) s = -1e9f;
      float mx = s;
#pragma unroll
      for (int off = 1; off < 32; off <<= 1) mx = fmaxf(mx, __shfl_xor(mx, off, 32));
      float ex = __expf(s - mx);
      float sm = ex;
#pragma unroll
      for (int off = 1; off < 32; off <<= 1) sm += __shfl_xor(sm, off, 32);
      float p = ex / sm;
      p_l[head][item][key] = p;
      attnout[(b0 + item) * 128 + head * 32 + key] = p;
    }
  }
  __syncthreads();
  if (part == 1) {
    // ---- PV from V fragments. Lane holds V[r][d=nt*16+lr]. ----
    float po[2][4];
#pragma unroll
    for (int item = 0; item < 2; ++item)
#pragma unroll
      for (int nt = 0; nt < 4; ++nt) po[item][nt] = 0.f;
#pragma unroll
    for (int mt = 0; mt < 4; ++mt)
#pragma unroll
      for (int j = 0; j < 4; ++j) {
        int r = mt * 16 + lkg * 4 + j;
        if (r < 2 * NE) {
          int item = (r >= NE) ? 1 : 0;
          float p = p_l[head][item][1 + (r - item * NE)];
#pragma unroll
          for (int nt = 0; nt < 4; ++nt)
            po[item][nt] = fmaf(p, acc[mt][nt][j], po[item][nt]);
        }
      }
#pragma unroll
    for (int item = 0; item < 2; ++item)
#pragma unroll
      for (int nt = 0; nt < 4; ++nt) {
        float t = po[item][nt];
        t += __shfl_xor(t, 16, 64);
        t += __shfl_xor(t, 32, 64);
        po[item][nt] = t;
      }
    if (lkg == 0) {
#pragma unroll
      for (int item = 0; item < 2; ++item)
#pragma unroll
        for (int nt = 0; nt < 4; ++nt) {
          int d = nt * 16 + lr;
          float vego = b2f(qk_l[item * 768 + 512 + head * 64 + d]);
          float o = po[item][nt] + p_l[head][item][0] * vego;
          valout[(b0 + item) * 256 + head * 64 + d] = f2b(o);
        }
    }
  }
}

// ---------------- K3: res = (value @ Wc^T + ego) * 0.5 --------------------------------
__global__ __launch_bounds__(256, 2)
void k3_out(const unsigned short* __restrict__ val, const unsigned short* __restrict__ wc,
            const float* __restrict__ ego, float* __restrict__ out) {
  __shared__ __align__(16) unsigned short Al[128 * 256];
  const int tid = threadIdx.x;
  const int bM = blockIdx.x * 128, bN = blockIdx.y * 64;
#pragma unroll
  for (int it = 0; it < 16; ++it) {
    int c = tid + it * 256;
    int row = c >> 5, k8 = c & 31;
    bf16x8 v = *(const bf16x8*)(val + (size_t)(bM + row) * 256 + k8 * 8);
    int byteoff = row * 512 + ((k8 * 16) ^ ((row & 7) << 4));
    *(bf16x8*)((char*)Al + byteoff) = v;
  }
  __syncthreads();
  const int w = tid >> 6, lane = tid & 63, lr = lane & 15, lkg = lane >> 4;
  f32x4 acc[2][4];
#pragma unroll
  for (int mt = 0; mt < 2; ++mt)
#pragma unroll
    for (int nt = 0; nt < 4; ++nt) acc[mt][nt] = (f32x4){0.f, 0.f, 0.f, 0.f};
#pragma unroll
  for (int kk = 0; kk < 8; ++kk) {
    int kidx = kk * 32 + lkg * 8;
    bf16x8 bfr[4], afr[2];
#pragma unroll
    for (int nt = 0; nt < 4; ++nt)
      bfr[nt] = *(const bf16x8*)(wc + (size_t)(bN + nt * 16 + lr) * 256 + kidx);
#pragma unroll
    for (int mt = 0; mt < 2; ++mt) {
      int row = w * 32 + mt * 16 + lr;
      int byteoff = row * 512 + ((kidx * 2) ^ ((row & 7) << 4));
      afr[mt] = *(const bf16x8*)((const char*)Al + byteoff);
    }
#pragma unroll
    for (int mt = 0; mt < 2; ++mt)
#pragma unroll
      for (int nt = 0; nt < 4; ++nt)
        acc[mt][nt] = __builtin_amdgcn_mfma_f32_16x16x32_bf16(afr[mt], bfr[nt], acc[mt][nt], 0, 0, 0);
  }
#pragma unroll
  for (int mt = 0; mt < 2; ++mt)
#pragma unroll
    for (int nt = 0; nt < 4; ++nt)
#pragma unroll
      for (int j = 0; j < 4; ++j) {
        int row = bM + w * 32 + mt * 16 + lkg * 4 + j;
        int col = bN + nt * 16 + lr;
        out[(size_t)row * 256 + col] = (acc[mt][nt][j] + ego[(size_t)row * 256 + col]) * 0.5f;
      }
}

extern "C" void kernel_launch(void* const* d_in, const int* in_sizes, int n_in,
                              void* d_out, int out_size, void* d_ws, size_t ws_size,
                              hipStream_t stream) {
  const float* ego    = (const float*)d_in[0];
  const float* others = (const float*)d_in[1];
  const int*   mask   = (const int*)d_in[2];
  const float* wq  = (const float*)d_in[3];
  const float* wk  = (const float*)d_in[4];
  const float* wv  = (const float*)d_in[5];
  const float* wok = (const float*)d_in[6];
  const float* wov = (const float*)d_in[7];
  const float* wc  = (const float*)d_in[8];

  unsigned short* ws_w   = (unsigned short*)d_ws;            // 6*65536 bf16
  unsigned short* ws_qkv = ws_w + 6 * 65536;                 // NB*768 bf16
  unsigned short* ws_val = ws_qkv + (size_t)NB * 768;        // NB*256 bf16

  float* res  = (float*)d_out;                               // NB*256 f32
  float* attn = res + (size_t)NB * 256;                      // NB*128 f32

  hipLaunchKernelGGL(k0_conv, dim3(256, 6), dim3(256), 0, stream,
                     wq, wk, wv, wok, wov, wc, ws_w);
  hipLaunchKernelGGL(k1_qkv, dim3(128, 12), dim3(256), 0, stream,
                     ego, ws_w, ws_qkv);
  hipLaunchKernelGGL(k2_attn, dim3(8192), dim3(512), 0, stream,
                     others, mask, ws_w + 3 * 65536, ws_qkv, ws_val, attn);
  hipLaunchKernelGGL(k3_out, dim3(128, 4), dim3(256), 0, stream,
                     ws_val, ws_w + 5 * 65536, ego, res);
}

// Round 3
// 268.066 us; speedup vs baseline: 1.6399x; 1.3703x over previous
//
#include <hip/hip_runtime.h>
#include <hip/hip_bf16.h>

typedef __attribute__((ext_vector_type(8))) short bf16x8;
typedef __attribute__((ext_vector_type(4))) float f32x4;

#define NB 16384
#define NE 31

static __device__ __forceinline__ unsigned short f2b(float f) {
  unsigned int u = __builtin_bit_cast(unsigned int, f);
  return (unsigned short)((u + 0x7fffu + ((u >> 16) & 1u)) >> 16);
}
static __device__ __forceinline__ float b2f(unsigned short h) {
  return __builtin_bit_cast(float, ((unsigned int)h) << 16);
}

// ---------------------------------------------------------------------------
// Weight preprocessing.
// W1 (bf16 [1792][256]):
//   rows 0..255    = 0.125*Wq      (ego q, pre-scaled by 1/sqrt(64))
//   rows 256..511  = Wk
//   rows 512..767  = Wv
//   rows 768..1791 = Wqo: row 768 + h*256 + c, col k =
//                    sum_d 0.125*Wq[h*64+d][k] * Wok[h*64+d][c]
// W2 (bf16 [256][1280]): out row n:
//   cols h*256+c (h<4)  = sum_d Wov[h*64+d][c] * Wc[n][h*64+d]
//   cols 1024 + m'      = Wc[n][m']
// ---------------------------------------------------------------------------

__global__ void k0_base(const float* __restrict__ wq, const float* __restrict__ wk,
                        const float* __restrict__ wv, const float* __restrict__ wc,
                        unsigned short* __restrict__ W1, unsigned short* __restrict__ W2) {
  int r = blockIdx.x, k = threadIdx.x;
  if (r < 256) {
    W1[r * 256 + k] = f2b(0.125f * wq[r * 256 + k]);
  } else if (r < 512) {
    W1[r * 256 + k] = f2b(wk[(r - 256) * 256 + k]);
  } else if (r < 768) {
    W1[r * 256 + k] = f2b(wv[(r - 512) * 256 + k]);
  } else {
    int n = r - 768;  // 0..255
    W2[n * 1280 + 1024 + k] = f2b(wc[n * 256 + k]);
  }
}

__global__ void k0_wqo(const float* __restrict__ wq, const float* __restrict__ wok,
                       unsigned short* __restrict__ W1) {
  int m = blockIdx.x;          // 0..1023
  int k = threadIdx.x;         // 0..255
  int h = m >> 8, c = m & 255;
  float acc = 0.f;
#pragma unroll 8
  for (int d = 0; d < 64; ++d)
    acc = fmaf(wq[(h * 64 + d) * 256 + k], wok[(h * 64 + d) * 256 + c], acc);
  W1[(768 + m) * 256 + k] = f2b(0.125f * acc);
}

__global__ void k0_g(const float* __restrict__ wov, const float* __restrict__ wc,
                     unsigned short* __restrict__ W2) {
  int n = blockIdx.x;          // 0..255
  int t = threadIdx.x;         // 0..255 (= c)
#pragma unroll 1
  for (int mi = 0; mi < 4; ++mi) {  // head
    float acc = 0.f;
#pragma unroll 8
    for (int d = 0; d < 64; ++d)
      acc = fmaf(wov[(mi * 64 + d) * 256 + t], wc[n * 256 + mi * 64 + d], acc);
    W2[n * 1280 + mi * 256 + t] = f2b(acc);
  }
}

// ---------------------------------------------------------------------------
// k1b: qkv2[b][n] = sum_k ego[b][k] * W1[n][k], n in [0,1792). bf16 out.
// Per wg: 64 rows, 4 waves, each wave a 448-col stripe (7 blocks of 64).
// ---------------------------------------------------------------------------
__global__ __launch_bounds__(256, 2)
void k1b(const float* __restrict__ ego, const unsigned short* __restrict__ W1,
         unsigned short* __restrict__ qkv2) {
  __shared__ __align__(16) unsigned short Al[64 * 256];  // 32KB, swizzled
  const int tid = threadIdx.x;
  const int bM = blockIdx.x * 64;
#pragma unroll
  for (int it = 0; it < 8; ++it) {
    int c = tid + it * 256;                // 2048 chunks of 8 f32
    int row = c >> 5, k8 = c & 31;
    const float4* g = (const float4*)(ego + (size_t)(bM + row) * 256 + k8 * 8);
    float4 x = g[0], y = g[1];
    float t[8] = {x.x, x.y, x.z, x.w, y.x, y.y, y.z, y.w};
    bf16x8 v;
#pragma unroll
    for (int j = 0; j < 8; ++j) v[j] = (short)f2b(t[j]);
    int byteoff = row * 512 + ((k8 * 16) ^ ((row & 7) << 4));
    *(bf16x8*)((char*)Al + byteoff) = v;
  }
  __syncthreads();
  const int w = tid >> 6, lane = tid & 63, lr = lane & 15, lkg = lane >> 4;
#pragma unroll 1
  for (int cb = 0; cb < 7; ++cb) {
    int bN = w * 448 + cb * 64;
    f32x4 acc[4][4];
#pragma unroll
    for (int mt = 0; mt < 4; ++mt)
#pragma unroll
      for (int nt = 0; nt < 4; ++nt) acc[mt][nt] = (f32x4){0.f, 0.f, 0.f, 0.f};
#pragma unroll
    for (int kk = 0; kk < 8; ++kk) {
      int kidx = kk * 32 + lkg * 8;
      bf16x8 bfr[4];
#pragma unroll
      for (int nt = 0; nt < 4; ++nt)
        bfr[nt] = *(const bf16x8*)(W1 + (size_t)(bN + nt * 16 + lr) * 256 + kidx);
#pragma unroll
      for (int mt = 0; mt < 4; ++mt) {
        int row = mt * 16 + lr;
        int byteoff = row * 512 + ((kidx * 2) ^ ((row & 7) << 4));
        bf16x8 a = *(const bf16x8*)((const char*)Al + byteoff);
#pragma unroll
        for (int nt = 0; nt < 4; ++nt)
          acc[mt][nt] = __builtin_amdgcn_mfma_f32_16x16x32_bf16(a, bfr[nt], acc[mt][nt], 0, 0, 0);
      }
    }
#pragma unroll
    for (int mt = 0; mt < 4; ++mt)
#pragma unroll
      for (int nt = 0; nt < 4; ++nt)
#pragma unroll
        for (int j = 0; j < 4; ++j) {
          int row = bM + mt * 16 + lkg * 4 + j;
          int col = bN + nt * 16 + lr;
          qkv2[(size_t)row * 1792 + col] = f2b(acc[mt][nt][j]);
        }
  }
}

// ---------------------------------------------------------------------------
// ks_attn: per item. Reads others row-block (31x256 f32), qkv2 row (1792 bf16).
// scores via MFMA (Qo . x), s0 via VALU (q . k_ego), masked softmax,
// ctx_h = sum_e p x_e, writes u[b][1280] = [ctx_0..ctx_3 ; p0*v_ego], attn probs.
// ---------------------------------------------------------------------------
__global__ __launch_bounds__(256, 4)
void ks_attn(const float* __restrict__ others, const int* __restrict__ mask,
             const unsigned short* __restrict__ qkv2,
             unsigned short* __restrict__ u,
             float* __restrict__ attnout) {
  __shared__ __align__(16) unsigned short Xr[32 * 264];   // 16.5KB, stride 264 elems
  __shared__ __align__(16) unsigned short Qo_l[1024];     // 4 heads x 256
  __shared__ __align__(16) unsigned short qk_l[768];      // q,k,v ego (q pre-scaled)
  __shared__ float sco_l[4][32];
  __shared__ float Pl[4][32];
  const int tid = threadIdx.x;
  const size_t b = blockIdx.x;

  // ---- stage X (bf16) + qkv2 row ----
  {
    int e = tid >> 3, c = tid & 7;
    if (e < 31) {
      const float4* src = (const float4*)(others) + ((b * 31 + e) * 64 + c * 8);
      float4 f[8];
#pragma unroll
      for (int j = 0; j < 8; ++j) f[j] = src[j];
#pragma unroll
      for (int j = 0; j < 4; ++j) {
        bf16x8 v;
        v[0] = (short)f2b(f[2 * j].x);     v[1] = (short)f2b(f[2 * j].y);
        v[2] = (short)f2b(f[2 * j].z);     v[3] = (short)f2b(f[2 * j].w);
        v[4] = (short)f2b(f[2 * j + 1].x); v[5] = (short)f2b(f[2 * j + 1].y);
        v[6] = (short)f2b(f[2 * j + 1].z); v[7] = (short)f2b(f[2 * j + 1].w);
        *(bf16x8*)(&Xr[e * 264 + c * 32 + j * 8]) = v;
      }
    } else {
      bf16x8 z = (bf16x8){0, 0, 0, 0, 0, 0, 0, 0};
#pragma unroll
      for (int j = 0; j < 4; ++j) *(bf16x8*)(&Xr[31 * 264 + c * 32 + j * 8]) = z;
    }
    if (tid < 224) {
      bf16x8 v = *(const bf16x8*)(qkv2 + b * 1792 + tid * 8);
      if (tid < 96) *(bf16x8*)(&qk_l[tid * 8]) = v;
      else          *(bf16x8*)(&Qo_l[(tid - 96) * 8]) = v;
    }
  }
  __syncthreads();

  const int w = tid >> 6, lane = tid & 63, lr = lane & 15, lkg = lane >> 4;

  // ---- scores ----
  if (w < 2) {
    // S[m][n] = Qo[m] . x_n   (m = head, n = entity); wave w covers n = w*16..w*16+15
    f32x4 acc = (f32x4){0.f, 0.f, 0.f, 0.f};
#pragma unroll
    for (int kk = 0; kk < 8; ++kk) {
      bf16x8 a = *(const bf16x8*)(&Qo_l[(lr & 3) * 256 + kk * 32 + lkg * 8]);
      bf16x8 bb = *(const bf16x8*)(&Xr[(w * 16 + lr) * 264 + kk * 32 + lkg * 8]);
      acc = __builtin_amdgcn_mfma_f32_16x16x32_bf16(a, bb, acc, 0, 0, 0);
    }
    if (lkg == 0) {
      int n = w * 16 + lr;
      if (n < NE) {
#pragma unroll
        for (int j = 0; j < 4; ++j) sco_l[j][1 + n] = acc[j];
      }
    }
  } else if (w == 2) {
    // s0[h] = q_h . k_ego_h (q pre-scaled)
    int h = lane >> 4, i = lane & 15;
    const unsigned short* q4 = &qk_l[h * 64 + i * 4];
    const unsigned short* k4p = &qk_l[256 + h * 64 + i * 4];
    float s = 0.f;
#pragma unroll
    for (int j = 0; j < 4; ++j) s += b2f(q4[j]) * b2f(k4p[j]);
#pragma unroll
    for (int off = 1; off < 16; off <<= 1) s += __shfl_xor(s, off, 16);
    if (i == 0) sco_l[h][0] = s;
  }
  __syncthreads();

  // ---- masked softmax: wave w = head w (lanes 32..63 compute duplicate) ----
  {
    int key = lane & 31;
    float s = sco_l[w][key];
    if (mask[b * 32 + key] != 0) s = -1e9f;
    float mx = s;
#pragma unroll
    for (int off = 1; off < 32; off <<= 1) mx = fmaxf(mx, __shfl_xor(mx, off, 32));
    float ex = __expf(s - mx);
    float sm = ex;
#pragma unroll
    for (int off = 1; off < 32; off <<= 1) sm += __shfl_xor(sm, off, 32);
    float p = ex / sm;
    if (lane < 32) {
      Pl[w][key] = p;
      attnout[b * 128 + w * 32 + key] = p;
    }
  }
  // (no barrier: wave w only consumes Pl[w], which it wrote itself)

  // ---- ctx_h = sum_e p_e x_e ; u = [ctx ; p0*v_ego] ----
  {
    float a0 = 0.f, a1 = 0.f, a2 = 0.f, a3 = 0.f;
#pragma unroll
    for (int e = 0; e < NE; ++e) {
      float p = Pl[w][1 + e];
      ushort4 xv = *(const ushort4*)(&Xr[e * 264 + lane * 4]);
      a0 = fmaf(p, b2f(xv.x), a0);
      a1 = fmaf(p, b2f(xv.y), a1);
      a2 = fmaf(p, b2f(xv.z), a2);
      a3 = fmaf(p, b2f(xv.w), a3);
    }
    ushort4 st;
    st.x = f2b(a0); st.y = f2b(a1); st.z = f2b(a2); st.w = f2b(a3);
    *(ushort4*)(u + b * 1280 + w * 256 + lane * 4) = st;
    float p0 = Pl[w][0];
    u[b * 1280 + 1024 + w * 64 + lane] = f2b(p0 * b2f(qk_l[512 + w * 64 + lane]));
  }
}

// ---------------------------------------------------------------------------
// k4: res[b][n] = (sum_m u[b][m]*W2[n][m] + ego[b][n]) * 0.5
// Per wg: 32 rows, K looped in 5 chunks of 256; 4 waves = 64-col stripes.
// ---------------------------------------------------------------------------
__global__ __launch_bounds__(256, 2)
void k4_out(const unsigned short* __restrict__ u, const unsigned short* __restrict__ W2,
            const float* __restrict__ ego, float* __restrict__ out) {
  __shared__ __align__(16) unsigned short Au[32 * 256];  // 16KB, swizzled
  const int tid = threadIdx.x;
  const int bM = blockIdx.x * 32;
  const int w = tid >> 6, lane = tid & 63, lr = lane & 15, lkg = lane >> 4;
  f32x4 acc[2][4];
#pragma unroll
  for (int mt = 0; mt < 2; ++mt)
#pragma unroll
    for (int nt = 0; nt < 4; ++nt) acc[mt][nt] = (f32x4){0.f, 0.f, 0.f, 0.f};
#pragma unroll 1
  for (int kc = 0; kc < 5; ++kc) {
#pragma unroll
    for (int it = 0; it < 4; ++it) {
      int c = tid + it * 256;              // 1024 chunks of 8 bf16
      int row = c >> 5, k8 = c & 31;
      bf16x8 v = *(const bf16x8*)(u + (size_t)(bM + row) * 1280 + kc * 256 + k8 * 8);
      int byteoff = row * 512 + ((k8 * 16) ^ ((row & 7) << 4));
      *(bf16x8*)((char*)Au + byteoff) = v;
    }
    __syncthreads();
#pragma unroll
    for (int kk = 0; kk < 8; ++kk) {
      int kidx = kk * 32 + lkg * 8;
      bf16x8 bfr[4];
#pragma unroll
      for (int nt = 0; nt < 4; ++nt)
        bfr[nt] = *(const bf16x8*)(W2 + (size_t)(w * 64 + nt * 16 + lr) * 1280 + kc * 256 + kidx);
#pragma unroll
      for (int mt = 0; mt < 2; ++mt) {
        int row = mt * 16 + lr;
        int byteoff = row * 512 + ((kidx * 2) ^ ((row & 7) << 4));
        bf16x8 a = *(const bf16x8*)((const char*)Au + byteoff);
#pragma unroll
        for (int nt = 0; nt < 4; ++nt)
          acc[mt][nt] = __builtin_amdgcn_mfma_f32_16x16x32_bf16(a, bfr[nt], acc[mt][nt], 0, 0, 0);
      }
    }
    __syncthreads();
  }
#pragma unroll
  for (int mt = 0; mt < 2; ++mt)
#pragma unroll
    for (int nt = 0; nt < 4; ++nt)
#pragma unroll
      for (int j = 0; j < 4; ++j) {
        int row = bM + mt * 16 + lkg * 4 + j;
        int col = w * 64 + nt * 16 + lr;
        out[(size_t)row * 256 + col] = (acc[mt][nt][j] + ego[(size_t)row * 256 + col]) * 0.5f;
      }
}

extern "C" void kernel_launch(void* const* d_in, const int* in_sizes, int n_in,
                              void* d_out, int out_size, void* d_ws, size_t ws_size,
                              hipStream_t stream) {
  const float* ego    = (const float*)d_in[0];
  const float* others = (const float*)d_in[1];
  const int*   mask   = (const int*)d_in[2];
  const float* wq  = (const float*)d_in[3];
  const float* wk  = (const float*)d_in[4];
  const float* wv  = (const float*)d_in[5];
  const float* wok = (const float*)d_in[6];
  const float* wov = (const float*)d_in[7];
  const float* wc  = (const float*)d_in[8];

  unsigned short* W1   = (unsigned short*)d_ws;                 // 1792*256
  unsigned short* W2   = W1 + 1792 * 256;                       // 256*1280
  unsigned short* qkv2 = W2 + 256 * 1280;                       // NB*1792
  unsigned short* u    = qkv2 + (size_t)NB * 1792;              // NB*1280

  float* res  = (float*)d_out;                                  // NB*256 f32
  float* attn = res + (size_t)NB * 256;                         // NB*128 f32

  hipLaunchKernelGGL(k0_base, dim3(1024), dim3(256), 0, stream, wq, wk, wv, wc, W1, W2);
  hipLaunchKernelGGL(k0_wqo,  dim3(1024), dim3(256), 0, stream, wq, wok, W1);
  hipLaunchKernelGGL(k0_g,    dim3(256),  dim3(256), 0, stream, wov, wc, W2);
  hipLaunchKernelGGL(k1b,     dim3(256),  dim3(256), 0, stream, ego, W1, qkv2);
  hipLaunchKernelGGL(ks_attn, dim3(NB),   dim3(256), 0, stream, others, mask, qkv2, u, attn);
  hipLaunchKernelGGL(k4_out,  dim3(512),  dim3(256), 0, stream, u, W2, ego, res);
}